// Round 7
// baseline (2110.878 us; speedup 1.0000x reference)
//
#include <hip/hip_runtime.h>
#include <stdint.h>

// Problem constants
#define B_ 16
#define S_ 256
#define E_ 512
#define H_ 1024
#define V_ 32000
#define R_ (B_*S_)        // 4096 rows (t*16 + b)
#define NCHUNK 250        // V / 128 column blocks

typedef __attribute__((ext_vector_type(8))) short bf16x8;   // 8 bf16 = 4 VGPRs
typedef __attribute__((ext_vector_type(4))) float f32x4;

// ---- helpers -------------------------------------------------------------

__device__ __forceinline__ unsigned short f2bf(float f) {   // RNE f32->bf16
  unsigned u = __float_as_uint(f);
  unsigned r = (u + 0x7FFFu + ((u >> 16) & 1u)) >> 16;
  return (unsigned short)r;
}

__device__ __forceinline__ void gl_lds16(const void* gsrc, void* ldst) {
  // async global->LDS, 16B/lane; LDS dest = wave-uniform base + lane*16
  __builtin_amdgcn_global_load_lds(
      (const __attribute__((address_space(1))) void*)gsrc,
      (__attribute__((address_space(3))) void*)ldst, 16, 0, 0);
}

__device__ __forceinline__ float dot4(float4 a, float4 b) {
  return a.x * b.x + a.y * b.y + a.z * b.z + a.w * b.w;
}

// ---- kernel 1: fused prologue --------------------------------------------
// Blocks 0..255: xp[t][b][j] = x[b][t][:].W_ih[j][:] + b_ih[j] + b_hh[j]
//   (one block per timestep t; x staged in LDS, W_ih streamed, VALU-bound).
// Blocks 256..2047: Vw f32 -> bf16 grid-stride convert (HBM-bound).
// The two paths stress disjoint pipes (VALU vs HBM); fusing overlaps them,
// replacing ~60 us serial with ~35 us. Branch is block-uniform.

__global__ __launch_bounds__(256, 2) void k_pre(
    const float* __restrict__ x, const float* __restrict__ Wih,
    const float* __restrict__ bih, const float* __restrict__ bhh,
    const float* __restrict__ Vw,
    float* __restrict__ xp, unsigned short* __restrict__ vwb) {
  const int tid = threadIdx.x;
  __shared__ __align__(16) float xl[B_][E_];
  if (blockIdx.x < S_) {
    // ---- xp path ----
    const int t = blockIdx.x;
    {
      const float4* xg = (const float4*)x;
      float4* xl4 = (float4*)&xl[0][0];
#pragma unroll
      for (int i = 0; i < 8; ++i) {
        int L = tid + 256 * i;            // 0..2047 f4s
        int b = L >> 7, e4 = L & 127;
        xl4[L] = xg[(size_t)(b * S_ + t) * (E_ / 4) + e4];
      }
    }
    __syncthreads();
    float bias[4];
#pragma unroll
    for (int c = 0; c < 4; ++c) bias[c] = bih[tid * 4 + c] + bhh[tid * 4 + c];
    float acc[4][B_];
#pragma unroll
    for (int c = 0; c < 4; ++c)
#pragma unroll
      for (int b = 0; b < B_; ++b) acc[c][b] = 0.f;
    const float4* W4 = (const float4*)Wih;
    for (int e4 = 0; e4 < E_ / 4; ++e4) {
      float4 w[4];
#pragma unroll
      for (int c = 0; c < 4; ++c) w[c] = W4[(size_t)(tid * 4 + c) * (E_ / 4) + e4];
#pragma unroll
      for (int b = 0; b < B_; ++b) {
        float4 xv = *(const float4*)&xl[b][e4 * 4];
#pragma unroll
        for (int c = 0; c < 4; ++c)
          acc[c][b] += w[c].x * xv.x + w[c].y * xv.y + w[c].z * xv.z + w[c].w * xv.w;
      }
    }
#pragma unroll
    for (int b = 0; b < B_; ++b) {
      float4 o;
      o.x = acc[0][b] + bias[0]; o.y = acc[1][b] + bias[1];
      o.z = acc[2][b] + bias[2]; o.w = acc[3][b] + bias[3];
      *(float4*)&xp[((size_t)t * B_ + b) * H_ + tid * 4] = o;
    }
  } else {
    // ---- Vw convert path ----
    const long long n4 = (long long)V_ * H_ / 4;  // 8,192,000 float4s
    long long idx = (long long)(blockIdx.x - S_) * 256 + tid;
    const long long stride = (long long)(2048 - S_) * 256;
    const float4* src = (const float4*)Vw;
    ushort4* dst = (ushort4*)vwb;
    for (long long i = idx; i < n4; i += stride) {
      float4 v = src[i];
      ushort4 o;
      o.x = f2bf(v.x); o.y = f2bf(v.y); o.z = f2bf(v.z); o.w = f2bf(v.w);
      dst[i] = o;
    }
  }
}

// ---- kernel 2: persistent RNN scan ---------------------------------------
// 256 WGs x 256 thr = 8 groups (bg = blockIdx&7; batches {2bg, 2bg+1}) x 32
// col-groups (cg: cols 32cg..+31). Wave wv owns 8 cols j0 = 32cg + 8wv.
// Lane split: kk = lane&15 owns k-chunk [64kk,64kk+64); cc = lane>>4 owns
// col pair {j0+2cc, j0+2cc+1}. W slice = 128 f32 in REGISTERS. Per step:
// 4 partials (2c x 2b) x 256 FMA, 4-step butterfly over kk bits (16 shfl),
// tanh, publish. Publication is WRITE-THROUGH: packed agent-scope relaxed
// atomic stores (sc0/sc1 -> commit at MALL); __syncthreads' vmcnt(0) drain
// makes them durable BEFORE tid0's atomicAdd -- release ordering with no
// cache-wide wbl2 on the critical path. Consumer h-lines are provably cold
// (each outf row is read exactly once, after its write), so a
// workgroup-scope acquire (compiler fence) after the spin suffices.

__global__ __launch_bounds__(256, 1) void k_rnn(
    const float* __restrict__ xp, const float* __restrict__ Whh,
    const float* __restrict__ h0,
    float* __restrict__ outf, unsigned short* __restrict__ outb,
    unsigned* __restrict__ bar) {
  const int bg = blockIdx.x & 7;           // barrier/batch group
  const int cg = blockIdx.x >> 3;          // col group 0..31
  const int tid = threadIdx.x;
  const int wv = tid >> 6, lane = tid & 63;
  const int j0 = cg * 32 + wv * 8;
  const int kk = lane & 15;                // k-chunk index
  const int cc = lane >> 4;                // col-pair index 0..3
  // 96KB dummy LDS: forces 1 block/CU (256 blocks = 256 CUs) so no CU hosts
  // 2 blocks (a straggler would slow every barrier round). Guard can never
  // fire but is opaque to the compiler, keeping the allocation live.
  __shared__ int pad_[24576];
  if ((int)blockIdx.x == -1) pad_[tid] = tid;

  // W regs: w[c][i] = W_hh[j0+2cc+c][kk*64 + 4i .. +4]
  float4 w[2][16];
#pragma unroll
  for (int c = 0; c < 2; ++c)
#pragma unroll
    for (int i = 0; i < 16; ++i)
      w[c][i] = *(const float4*)&Whh[(size_t)(j0 + 2 * cc + c) * H_ +
                                     kk * 64 + 4 * i];
  unsigned* gbar = bar + bg * 8 * 64;      // 8 stripes, 256B apart
  unsigned expect = 0;
  for (int t = 0; t < S_; ++t) {
    const float* hsrc = (t == 0)
        ? (h0 + (size_t)(bg * 2) * H_)
        : (outf + ((size_t)(t - 1) * B_ + bg * 2) * H_);
    float xpv[2][2];
    if (kk == 0) {                         // issue early; used after reduce
#pragma unroll
      for (int c = 0; c < 2; ++c)
#pragma unroll
        for (int b = 0; b < 2; ++b)
          xpv[c][b] = xp[((size_t)t * B_ + bg * 2 + b) * H_ + j0 + 2 * cc + c];
    }
    float4 hr[2][16];
#pragma unroll
    for (int b = 0; b < 2; ++b)
#pragma unroll
      for (int i = 0; i < 16; ++i)
        hr[b][i] = *(const float4*)&hsrc[(size_t)b * H_ + kk * 64 + 4 * i];
    float acc[2][2] = {{0.f, 0.f}, {0.f, 0.f}};
#pragma unroll
    for (int i = 0; i < 16; ++i)
#pragma unroll
      for (int c = 0; c < 2; ++c)
#pragma unroll
        for (int b = 0; b < 2; ++b)
          acc[c][b] += dot4(w[c][i], hr[b][i]);
    // butterfly over the 16-way k split (kk bits only)
#pragma unroll
    for (int m = 1; m < 16; m <<= 1)
#pragma unroll
      for (int c = 0; c < 2; ++c)
#pragma unroll
        for (int b = 0; b < 2; ++b)
          acc[c][b] += __shfl_xor(acc[c][b], m, 64);
    if (kk == 0) {                         // lanes 0,16,32,48 publish 4 each
#pragma unroll
      for (int b = 0; b < 2; ++b) {
        float hv[2];
#pragma unroll
        for (int c = 0; c < 2; ++c) {
          float z = acc[c][b] + xpv[c][b];
          float ex = __expf(2.f * z);      // tanh(z) = 1 - 2/(e^2z + 1)
          hv[c] = 1.f - 2.f / (ex + 1.f);
        }
        const size_t o = ((size_t)t * B_ + bg * 2 + b) * H_ + j0 + 2 * cc;
        union { float f[2]; unsigned long long u; } pk;
        pk.f[0] = hv[0]; pk.f[1] = hv[1];
        __hip_atomic_store((unsigned long long*)&outf[o], pk.u,
                           __ATOMIC_RELAXED, __HIP_MEMORY_SCOPE_AGENT);
        unsigned ub = (unsigned)f2bf(hv[0]) | ((unsigned)f2bf(hv[1]) << 16);
        __hip_atomic_store((unsigned*)&outb[o], ub,
                           __ATOMIC_RELAXED, __HIP_MEMORY_SCOPE_AGENT);
      }
    }
    __syncthreads();                       // vmcnt(0): stores durable @MALL
    if (t < S_ - 1) {
      expect += 32;
      if (tid == 0) atomicAdd(&gbar[(cg & 7) * 64], 1u);
      if (tid < 8) {
        int guard = 0;
        while (true) {
          unsigned s = __hip_atomic_load(&gbar[tid * 64], __ATOMIC_RELAXED,
                                         __HIP_MEMORY_SCOPE_AGENT);
#pragma unroll
          for (int m = 1; m < 8; m <<= 1) s += __shfl_xor(s, m, 8);
          if (s >= expect) break;
          if (++guard > (1 << 15)) break;  // hang-breaker (pathology only)
          __builtin_amdgcn_s_sleep(1);
        }
        // workgroup-scope acquire: compiler fence, no cache invalidate
        (void)__hip_atomic_load(&gbar[tid * 64], __ATOMIC_ACQUIRE,
                                __HIP_MEMORY_SCOPE_WORKGROUP);
      }
      __syncthreads();
    }
  }
}

// ---- kernel 3: bf16 MFMA GEMM (out . Vw^T) with fused per-tile LSE -------
// 128x128 tile, BK=64, 4 waves 2x2, 16x16x32 bf16 MFMA, global_load_lds(16B)
// staging with pre-swizzled source + XOR-swizzled reads, fused row-max /
// sum-exp epilogue -> per (colchunk, row) partials (transposed layout).
// Block mapping: L2 super-tiles. Each XCD owns ONE fixed 4-row A panel
// (1 MB, L2-resident for the whole kernel) and streams B in 5-column
// stiles of 20 blocks (1.25 MB, reused by the 4 bm rows while L2-hot).
// MALL reads drop ~2 GB -> ~510 MB vs the bn-streaming order.

__global__ void k_gemm_lse(
    const unsigned short* __restrict__ A,   // out bf16 [4096][1024]
    const unsigned short* __restrict__ Bw,  // Vw bf16 [32000][1024]
    const float* __restrict__ Vb,
    float* __restrict__ pmax, float* __restrict__ psum) {
  const int bid = blockIdx.x;
  // bijective bid -> (bm, bn): xcd = bid&7 (round-robin bid->XCD is a perf
  // heuristic only), local = bid>>3 walks 50 stiles x 20 blocks.
  const int xcd = bid & 7;
  const int local = bid >> 3;              // 0..999
  const int bng = local / 20;              // 0..49
  const int pos = local % 20;              // 4 bm x 5 bn
  const int bm = xcd * 4 + pos / 5;        // 0..31
  const int bn = bng * 5 + pos % 5;        // 0..249
  const int tid = threadIdx.x;
  const int wid = tid >> 6, lane = tid & 63;
  const int wm = wid >> 1, wn = wid & 1;
  const int lrow = lane & 15, lkb = lane >> 4;
  const int sw = (lrow & 7) << 4;          // read-side XOR swizzle
  const int srow = lane >> 3;              // staging: row within 8-row chunk
  const int scol = 8 * ((lane & 7) ^ srow);// staging: pre-swizzled k offset
  __shared__ __align__(16) char As[128 * 64 * 2];
  __shared__ __align__(16) char Bs[128 * 64 * 2];
  f32x4 acc[4][4];
  f32x4 zero = {0.f, 0.f, 0.f, 0.f};
#pragma unroll
  for (int mi = 0; mi < 4; ++mi)
#pragma unroll
    for (int ni = 0; ni < 4; ++ni) acc[mi][ni] = zero;

  for (int kt = 0; kt < 16; ++kt) {
    __syncthreads();                       // previous compute reads done
#pragma unroll
    for (int p = 0; p < 4; ++p) {
      const int q = wid * 4 + p;           // chunk 0..15 (8 rows each)
      const size_t ar = (size_t)(bm * 128 + q * 8 + srow);
      gl_lds16(A + ar * H_ + kt * 64 + scol, As + q * 1024);
      const size_t br = (size_t)(bn * 128 + q * 8 + srow);
      gl_lds16(Bw + br * H_ + kt * 64 + scol, Bs + q * 1024);
    }
    __syncthreads();                       // barrier drains vmcnt(0)
#pragma unroll
    for (int ks = 0; ks < 2; ++ks) {
      bf16x8 av[4], bv[4];
#pragma unroll
      for (int mi = 0; mi < 4; ++mi) {
        const int r = wm * 64 + mi * 16 + lrow;
        av[mi] = *(const bf16x8*)(As + ((r * 128 + (ks * 32 + lkb * 8) * 2) ^ sw));
      }
#pragma unroll
      for (int ni = 0; ni < 4; ++ni) {
        const int r = wn * 64 + ni * 16 + lrow;
        bv[ni] = *(const bf16x8*)(Bs + ((r * 128 + (ks * 32 + lkb * 8) * 2) ^ sw));
      }
#pragma unroll
      for (int mi = 0; mi < 4; ++mi)
#pragma unroll
        for (int ni = 0; ni < 4; ++ni)
          acc[mi][ni] = __builtin_amdgcn_mfma_f32_16x16x32_bf16(
              av[mi], bv[ni], acc[mi][ni], 0, 0, 0);
    }
  }
  __syncthreads();                         // before reusing As as scratch
  // epilogue: C/D layout col=lane&15, row=(lane>>4)*4+reg  [m89/m91]
  float vb[4];
#pragma unroll
  for (int ni = 0; ni < 4; ++ni) vb[ni] = Vb[bn * 128 + wn * 64 + ni * 16 + lrow];
  float* scrm = (float*)As;                // [2][128]
  float* scrs = (float*)(As + 1024);       // [2][128]
#pragma unroll
  for (int mi = 0; mi < 4; ++mi) {
#pragma unroll
    for (int reg = 0; reg < 4; ++reg) {
      float v0 = acc[mi][0][reg] + vb[0];
      float v1 = acc[mi][1][reg] + vb[1];
      float v2 = acc[mi][2][reg] + vb[2];
      float v3 = acc[mi][3][reg] + vb[3];
      float mx = fmaxf(fmaxf(v0, v1), fmaxf(v2, v3));
#pragma unroll
      for (int m = 1; m < 16; m <<= 1) mx = fmaxf(mx, __shfl_xor(mx, m, 64));
      float se = __expf(v0 - mx) + __expf(v1 - mx) +
                 __expf(v2 - mx) + __expf(v3 - mx);
#pragma unroll
      for (int m = 1; m < 16; m <<= 1) se += __shfl_xor(se, m, 64);
      if (lrow == 0) {
        int r = wm * 64 + mi * 16 + lkb * 4 + reg;
        scrm[wn * 128 + r] = mx;
        scrs[wn * 128 + r] = se;
      }
    }
  }
  __syncthreads();
  if (tid < 128) {
    float m0 = scrm[tid], m1 = scrm[128 + tid];
    float s0 = scrs[tid], s1 = scrs[128 + tid];
    float M = fmaxf(m0, m1);
    float S = s0 * __expf(m0 - M) + s1 * __expf(m1 - M);
    size_t row = (size_t)bm * 128 + tid;
    pmax[(size_t)bn * R_ + row] = M;      // transposed: [chunk][row]
    psum[(size_t)bn * R_ + row] = S;
  }
}

// ---- kernel 4: exact f32 target logit ------------------------------------

__global__ void k_tgt(const float* __restrict__ outf, const float* __restrict__ Vw,
                      const float* __restrict__ Vb, const int* __restrict__ y,
                      float* __restrict__ tgt) {
  const int wid = threadIdx.x >> 6, lane = threadIdx.x & 63;
  const int r = blockIdx.x * 4 + wid;
  const int b = r & 15, t = r >> 4;
  const int yv = y[b * S_ + t];
  const float4* ar = (const float4*)(outf + (size_t)r * H_);
  const float4* br = (const float4*)(Vw + (size_t)yv * H_);
  float s = 0.f;
#pragma unroll
  for (int c = 0; c < 4; ++c) {
    float4 a = ar[lane + 64 * c], w = br[lane + 64 * c];
    s += a.x * w.x + a.y * w.y + a.z * w.z + a.w * w.w;
  }
#pragma unroll
  for (int m = 1; m < 64; m <<= 1) s += __shfl_xor(s, m, 64);
  if (lane == 0) tgt[r] = s + Vb[yv];
}

// ---- kernel 5: combine chunk partials -> nll[r] (coalesced) --------------

__global__ void k_comb(const float* __restrict__ pmax, const float* __restrict__ psum,
                       const float* __restrict__ tgt, float* __restrict__ nll) {
  const int r = blockIdx.x * 256 + threadIdx.x;
  float M = -1e30f;
  for (int c = 0; c < NCHUNK; ++c) M = fmaxf(M, pmax[(size_t)c * R_ + r]);
  float S = 0.f;
  for (int c = 0; c < NCHUNK; ++c)
    S += psum[(size_t)c * R_ + r] * __expf(pmax[(size_t)c * R_ + r] - M);
  nll[r] = M + logf(S) - tgt[r];
}

// ---- kernel 6: loss mean + h_n copy --------------------------------------

__global__ void k_fin(const float* __restrict__ nll, const float* __restrict__ outf,
                      float* __restrict__ out) {
  __shared__ float red[4];
  const int tid = threadIdx.x, lane = tid & 63, wid = tid >> 6;
  float s = 0.f;
#pragma unroll
  for (int i = 0; i < 16; ++i) s += nll[tid + 256 * i];
#pragma unroll
  for (int m = 1; m < 64; m <<= 1) s += __shfl_xor(s, m, 64);
  if (lane == 0) red[wid] = s;
  __syncthreads();
  if (tid == 0) out[0] = (red[0] + red[1] + red[2] + red[3]) * (1.0f / R_);
  // h_n copy: f4 loads (out+1 is 4B-misaligned, so stores stay scalar)
  const float4* hn4 = (const float4*)(outf + (size_t)(S_ - 1) * B_ * H_);
#pragma unroll
  for (int i = 0; i < 16; ++i) {
    const int j = tid + 256 * i;          // f4 index 0..4095
    float4 v = hn4[j];
    out[1 + 4 * j]     = v.x;
    out[2 + 4 * j]     = v.y;
    out[3 + 4 * j]     = v.z;
    out[4 + 4 * j]     = v.w;
  }
}

// ---- launch --------------------------------------------------------------
// ws layout (bytes), total ~110.6 MiB:
//   [0,16384)       barrier counters (8 groups x 8 stripes x 256B)
//   xp    f32 [256][16][1024]   16 MiB
//   outf  f32 [256][16][1024]   16 MiB
//   outb  bf16 [4096][1024]      8 MiB
//   vwb   bf16 [32000][1024]   62.5 MiB
//   pmax  f32 [250][4096]        4 MiB   (transposed [chunk][row])
//   psum  f32 [250][4096]        4 MiB
//   tgt   f32 [4096], nll f32 [4096]

extern "C" void kernel_launch(void* const* d_in, const int* in_sizes, int n_in,
                              void* d_out, int out_size, void* d_ws, size_t ws_size,
                              hipStream_t stream) {
  (void)in_sizes; (void)n_in; (void)out_size; (void)ws_size;
  const float* x   = (const float*)d_in[0];
  const int*   y   = (const int*)d_in[1];
  const float* h0  = (const float*)d_in[2];
  const float* Wih = (const float*)d_in[3];
  const float* Whh = (const float*)d_in[4];
  const float* bih = (const float*)d_in[5];
  const float* bhh = (const float*)d_in[6];
  const float* Vw  = (const float*)d_in[7];
  const float* Vb  = (const float*)d_in[8];
  float* out = (float*)d_out;

  char* ws = (char*)d_ws;
  unsigned* bar = (unsigned*)ws;
  float* xp   = (float*)(ws + 16384);
  float* outf = xp + (size_t)R_ * H_;
  unsigned short* outb = (unsigned short*)(outf + (size_t)R_ * H_);
  unsigned short* vwb  = outb + (size_t)R_ * H_;
  float* pmax = (float*)(vwb + (size_t)V_ * H_);
  float* psum = pmax + (size_t)NCHUNK * R_;
  float* tgt  = psum + (size_t)NCHUNK * R_;
  float* nll  = tgt + R_;

  hipMemsetAsync(bar, 0, 16384, stream);
  k_pre<<<2048, 256, 0, stream>>>(x, Wih, bih, bhh, Vw, xp, vwb);
  k_rnn<<<256, 256, 0, stream>>>(xp, Whh, h0, outf, outb, bar);
  k_gemm_lse<<<32 * NCHUNK, 256, 0, stream>>>(outb, vwb, Vb, pmax, psum);
  k_tgt<<<R_ / 4, 256, 0, stream>>>(outf, Vw, Vb, y, tgt);
  k_comb<<<R_ / 256, 256, 0, stream>>>(pmax, psum, tgt, nll);
  k_fin<<<1, 256, 0, stream>>>(nll, outf, out);
}